// Round 2
// baseline (316.961 us; speedup 1.0000x reference)
//
#include <hip/hip_runtime.h>
#include <hip/hip_bf16.h>

#define DM 1024
#define NH 16
#define DH 64
#define BB 4
#define SS 2048
#define MROWS (BB*SS)   // 8192

typedef unsigned short u16;
typedef short bf16x8 __attribute__((ext_vector_type(8)));
typedef short bf16x4 __attribute__((ext_vector_type(4)));
typedef float f32x4 __attribute__((ext_vector_type(4)));
typedef unsigned uintx2 __attribute__((ext_vector_type(2)));

#define MFMA16(a, b, c) __builtin_amdgcn_mfma_f32_16x16x32_bf16((a), (b), (c), 0, 0, 0)
#define MFMA16K16(a, b, c) __builtin_amdgcn_mfma_f32_16x16x16bf16_1k((a), (b), (c), 0, 0, 0)

__device__ __forceinline__ u16 f2bf(float f) {
  union { float f; unsigned u; } v; v.f = f;
  unsigned u = v.u;
  return (u16)((u + 0x7fffu + ((u >> 16) & 1u)) >> 16);
}

// pack two floats -> u32 of two RNE bf16 (lo = a, hi = b)
__device__ __forceinline__ unsigned pack2bf(float a, float b) {
  __hip_bfloat162 h = __float22bfloat162_rn(make_float2(a, b));
  unsigned u;
  __builtin_memcpy(&u, &h, 4);
  return u;
}

__device__ __forceinline__ bf16x8 ld_bf8(const u16* p) {
  return *(const bf16x8*)p;
}

// ---------------- convert x (fp32 -> bf16), 4 elems/thread ----------------
__global__ __launch_bounds__(256) void k_cvt_x(const float* __restrict__ x,
                                               u16* __restrict__ xb) {
  int i = (blockIdx.x * 256 + threadIdx.x) * 4;
  float4 v = *(const float4*)(x + i);
  ushort4 o;
  o.x = f2bf(v.x); o.y = f2bf(v.y); o.z = f2bf(v.z); o.w = f2bf(v.w);
  *(ushort4*)(xb + i) = o;
}

// ------------- transpose weights W[K,N] -> Wt[N,K] bf16, 4 segments -------
__global__ __launch_bounds__(1024) void k_tw(const float* __restrict__ Wq,
                                             const float* __restrict__ Wk,
                                             const float* __restrict__ Wv,
                                             const float* __restrict__ Wo,
                                             u16* __restrict__ Wt) {
  __shared__ float t[32][33];
  int k0 = blockIdx.x * 32;
  int seg = blockIdx.y >> 5;
  int n0 = (blockIdx.y & 31) * 32;
  const float* W = seg == 0 ? Wq : seg == 1 ? Wk : seg == 2 ? Wv : Wo;
  int tx = threadIdx.x, ty = threadIdx.y;
  t[ty][tx] = W[(size_t)(k0 + ty) * DM + n0 + tx];
  __syncthreads();
  Wt[(size_t)(seg * DM + n0 + ty) * DM + k0 + tx] = f2bf(t[tx][ty]);
}

// ---------------- GEMM: C[M,N] = A[M,K] * Bt[N,K]^T + bias ----------------
// (unchanged from R7)
__global__ __launch_bounds__(256) void k_gemm(
    const u16* __restrict__ A, const u16* __restrict__ Bt,
    int M, int N, int K,
    const float* __restrict__ b0, const float* __restrict__ b1,
    const float* __restrict__ b2,
    u16* __restrict__ oq, u16* __restrict__ ok, u16* __restrict__ ov,
    float* __restrict__ of, int mode) {
  __shared__ __align__(16) u16 As[128 * 32];
  __shared__ __align__(16) u16 Bs[128 * 32];
  int tid = threadIdx.x;
  int wave = tid >> 6, lane = tid & 63, quad = lane >> 4, l16 = lane & 15;
  int bm = blockIdx.x * 128, bn = blockIdx.y * 128;
  int wr = (wave >> 1) * 64, wc = (wave & 1) * 64;
  f32x4 acc[4][4] = {};

  const u16* ga = A + (size_t)(bm + wave * 32 + (lane >> 2)) * K + (lane & 3) * 8;
  const u16* gb = Bt + (size_t)(bn + wave * 32 + (lane >> 2)) * K + (lane & 3) * 8;
  u16* lda = &As[wave * 1024];
  u16* ldb = &Bs[wave * 1024];

  for (int k0 = 0; k0 < K; k0 += 32) {
#pragma unroll
    for (int i = 0; i < 2; ++i) {
      __builtin_amdgcn_global_load_lds(
          (const __attribute__((address_space(1))) void*)(ga + (size_t)i * 16 * K + k0),
          (__attribute__((address_space(3))) void*)(lda + i * 512), 16, 0, 0);
      __builtin_amdgcn_global_load_lds(
          (const __attribute__((address_space(1))) void*)(gb + (size_t)i * 16 * K + k0),
          (__attribute__((address_space(3))) void*)(ldb + i * 512), 16, 0, 0);
    }
    __syncthreads();
    bf16x8 af[4], bfr[4];
#pragma unroll
    for (int mi = 0; mi < 4; ++mi)
      af[mi] = *(const bf16x8*)(&As[(wr + mi * 16 + l16) * 32 + quad * 8]);
#pragma unroll
    for (int ni = 0; ni < 4; ++ni)
      bfr[ni] = *(const bf16x8*)(&Bs[(wc + ni * 16 + l16) * 32 + quad * 8]);
#pragma unroll
    for (int mi = 0; mi < 4; ++mi)
#pragma unroll
      for (int ni = 0; ni < 4; ++ni)
        acc[mi][ni] = MFMA16(af[mi], bfr[ni], acc[mi][ni]);
    __syncthreads();
  }

  if (mode == 0) {
#pragma unroll
    for (int mi = 0; mi < 4; ++mi)
#pragma unroll
      for (int ni = 0; ni < 4; ++ni)
#pragma unroll
        for (int r = 0; r < 4; ++r) {
          int row = bm + wr + mi * 16 + quad * 4 + r;
          int col = bn + wc + ni * 16 + l16;
          of[(size_t)row * N + col] = acc[mi][ni][r] + b0[col];
        }
  } else {
    int seg = bn >> 10;
    const float* bia = seg == 0 ? b0 : seg == 1 ? b1 : b2;
    int cb = bn & 1023;
    if (seg == 2) {
#pragma unroll
      for (int mi = 0; mi < 4; ++mi)
#pragma unroll
        for (int ni = 0; ni < 4; ++ni) {
          int row = bm + wr + mi * 16 + quad * 4;
          int col = cb + wc + ni * 16 + l16;
          float bv_ = bia[col];
          int bb2 = row >> 11, s = row & 2047, hh = col >> 6, dh = col & 63;
          ushort4 o4;
          o4.x = f2bf(acc[mi][ni][0] + bv_);
          o4.y = f2bf(acc[mi][ni][1] + bv_);
          o4.z = f2bf(acc[mi][ni][2] + bv_);
          o4.w = f2bf(acc[mi][ni][3] + bv_);
          *(ushort4*)(&ov[(((size_t)bb2 * NH + hh) * DH + dh) * SS + s]) = o4;
        }
    } else {
      u16* o = seg == 0 ? oq : ok;
      float sc = seg == 0 ? (0.125f * 1.44269504f) : 1.0f;
#pragma unroll
      for (int mi = 0; mi < 4; ++mi)
#pragma unroll
        for (int ni = 0; ni < 4; ++ni)
#pragma unroll
          for (int r = 0; r < 4; ++r) {
            int row = bm + wr + mi * 16 + quad * 4 + r;
            int col = cb + wc + ni * 16 + l16;
            float v = (acc[mi][ni][r] + bia[col]) * sc;
            int bb2 = row >> 11, s = row & 2047, hh = col >> 6, dh = col & 63;
            o[((((size_t)bb2 * NH + hh) * SS) + s) * DH + dh] = f2bf(v);
          }
    }
  }
}

// ---------------- flash attention (transposed-S, register P, DMA staging) --
// grid: (S/128, NH, BB), block 256 (4 waves, 32 q-rows each)
// R8 changes vs R7:
//  - XCD swizzle: all 16 q-tiles of one (b,h) land on one XCD -> its 512KB
//    K/V working set stays in that XCD's L2 (8 bh-groups * 512KB = 4MB = L2).
//  - next-tile DMA issued at the TOP of the step (writes buffer 1-P, reads
//    are from P) so the loads have the whole step to land before the
//    barrier's vmcnt(0) drain.
//  - normalizer via MFMA-of-ones against the packed P fragments (8 extra
//    K16 MFMAs/step on the underloaded MFMA pipe) instead of 64 VALU
//    bitops+adds/step (lrun). Identical semantics: sums the TRUNCATED bf16
//    P values in f32, so PV numerator and normalizer stay self-consistent.
//    Also removes the final cross-quad shuffles (every lane holds full sum).
//  - score accumulators seeded from a hoisted zero vector (dst != src2)
//    instead of per-tile zero-init movs.
__global__ __launch_bounds__(256) void k_attn(const u16* __restrict__ Q,
                                              const u16* __restrict__ Kg,
                                              const u16* __restrict__ VT,
                                              u16* __restrict__ ctx) {
  __shared__ __align__(16) u16 Ks[2][64][64];
  __shared__ __align__(16) u16 Vts[2][64][64];  // [d][kv], swizzled
  int tid = threadIdx.x;
  int wave = tid >> 6, lane = tid & 63, quad = lane >> 4, l16 = lane & 15;
  // XCD-aware remap: hardware RR assigns wgid%8 -> XCD. Give each XCD 8
  // whole (b,h) groups so their K/V (8*512KB) fits its 4MB L2.
  int g = blockIdx.x + gridDim.x * (blockIdx.y + gridDim.y * blockIdx.z);
  int xcd = g & 7, iw = g >> 3;
  int bh = xcd * 8 + (iw >> 4);  // 0..63
  int qtile = iw & 15;
  int h = bh & 15, b = bh >> 4;
  int q0 = qtile * 128;
  size_t bhoff = ((size_t)b * NH + h) * SS * DH;
  const u16* Qp = Q + bhoff + (size_t)(q0 + wave * 32) * DH;
  const u16* Kp = Kg + bhoff;
  const u16* Vp = VT + ((size_t)b * NH + h) * DH * SS;  // [Dh][S]

  // Q as B-operand fragments: B[k=d=quad*8+j][n=q=l16], 2 q-tiles
  bf16x8 qf[2][2];
#pragma unroll
  for (int qt = 0; qt < 2; ++qt) {
    qf[qt][0] = ld_bf8(Qp + (qt * 16 + l16) * DH + quad * 8);
    qf[qt][1] = ld_bf8(Qp + (qt * 16 + l16) * DH + 32 + quad * 8);
  }

  f32x4 Ot[4][2] = {};  // [d-tile][q-tile], O^T C-layout
  f32x4 Os[2] = {};     // normalizer accumulator (MFMA-of-ones), all rows equal
  const f32x4 fz = {0.0f, 0.0f, 0.0f, 0.0f};
  bf16x4 onesb;
  onesb[0] = onesb[1] = onesb[2] = onesb[3] = (short)0x3F80;  // bf16 1.0

  // ---- staging constants (global side carries the swizzle) ----
  int lrow = lane >> 3;            // 0..7 (row within 8-row DMA chunk)
  int lcb = (lane & 7) ^ lrow;     // swizzled global col-block
  const u16* kdma[2];
  const u16* vdma[2];
  u16* kl[2];
  u16* vl[2];
#pragma unroll
  for (int i = 0; i < 2; ++i) {
    int chunk = wave * 2 + i;      // 0..7, 8 rows each
    kdma[i] = Kp + (size_t)(chunk * 8 + lrow) * DH + lcb * 8;
    vdma[i] = Vp + (size_t)(chunk * 8 + lrow) * SS + lcb * 8;
    kl[i] = &Ks[0][chunk * 8][0];
    vl[i] = &Vts[0][chunk * 8][0];
  }

  // ---- hoisted frag pointers (loop addressing = base + literal) ----
  int e7 = l16 & 7, qh = quad >> 1, qp = quad & 1;
  const u16* kfr0 = &Ks[0][l16][(quad ^ e7) * 8];        // d-blocks 0..3
  const u16* kfr1 = &Ks[0][l16][((quad + 4) ^ e7) * 8];  // d-blocks 4..7
  const u16* vfr[4];
#pragma unroll
  for (int c = 0; c < 4; ++c)
    vfr[c] = &Vts[0][l16][((2 * c + qh) ^ e7) * 8 + qp * 4];

  // ---- prestage tile kv=0 into buffer 0 ----
#pragma unroll
  for (int i = 0; i < 2; ++i) {
    __builtin_amdgcn_global_load_lds(
        (const __attribute__((address_space(1))) void*)kdma[i],
        (__attribute__((address_space(3))) void*)kl[i], 16, 0, 0);
    __builtin_amdgcn_global_load_lds(
        (const __attribute__((address_space(1))) void*)vdma[i],
        (__attribute__((address_space(3))) void*)vl[i], 16, 0, 0);
  }
  __syncthreads();

  int kv = 64;  // next tile to stage

#define ATTN_STEP(P)                                                          \
  {                                                                           \
    if (kv < SS) {                                                            \
      _Pragma("unroll") for (int i = 0; i < 2; ++i) {                         \
        __builtin_amdgcn_global_load_lds(                                     \
            (const __attribute__((address_space(1))) void*)(kdma[i] +         \
                                                            (size_t)kv * DH), \
            (__attribute__((address_space(3))) void*)(kl[i] +                 \
                                                      (1 - (P)) * 4096),      \
            16, 0, 0);                                                        \
        __builtin_amdgcn_global_load_lds(                                     \
            (const __attribute__((address_space(1))) void*)(vdma[i] + kv),    \
            (__attribute__((address_space(3))) void*)(vl[i] +                 \
                                                      (1 - (P)) * 4096),      \
            16, 0, 0);                                                        \
      }                                                                       \
    }                                                                         \
    f32x4 s[2][4];                                                            \
    _Pragma("unroll") for (int t = 0; t < 4; ++t) {                           \
      bf16x8 kb0 = *(const bf16x8*)(kfr0 + (P) * 4096 + t * 1024);            \
      bf16x8 kb1 = *(const bf16x8*)(kfr1 + (P) * 4096 + t * 1024);            \
      _Pragma("unroll") for (int qt = 0; qt < 2; ++qt) {                      \
        f32x4 z = MFMA16(kb0, qf[qt][0], fz);                                 \
        z = MFMA16(kb1, qf[qt][1], z);                                        \
        s[qt][t] = z;                                                         \
      }                                                                       \
    }                                                                         \
    bf16x4 pb[2][4];                                                          \
    _Pragma("unroll") for (int qt = 0; qt < 2; ++qt)                          \
        _Pragma("unroll") for (int t = 0; t < 4; ++t) {                       \
      unsigned u0 = __builtin_bit_cast(                                       \
          unsigned, __builtin_amdgcn_exp2f(s[qt][t][0]));                     \
      unsigned u1 = __builtin_bit_cast(                                       \
          unsigned, __builtin_amdgcn_exp2f(s[qt][t][1]));                     \
      unsigned u2 = __builtin_bit_cast(                                       \
          unsigned, __builtin_amdgcn_exp2f(s[qt][t][2]));                     \
      unsigned u3 = __builtin_bit_cast(                                       \
          unsigned, __builtin_amdgcn_exp2f(s[qt][t][3]));                     \
      unsigned w0 = __builtin_amdgcn_perm(u1, u0, 0x07060302u);               \
      unsigned w1 = __builtin_amdgcn_perm(u3, u2, 0x07060302u);               \
      uintx2 w;                                                               \
      w[0] = w0;                                                              \
      w[1] = w1;                                                              \
      pb[qt][t] = __builtin_bit_cast(bf16x4, w);                              \
    }                                                                         \
    _Pragma("unroll") for (int qt = 0; qt < 2; ++qt)                          \
        _Pragma("unroll") for (int c = 0; c < 4; ++c)                         \
            Os[qt] = MFMA16K16(onesb, pb[qt][c], Os[qt]);                     \
    _Pragma("unroll") for (int c = 0; c < 4; ++c)                             \
        _Pragma("unroll") for (int dt = 0; dt < 4; ++dt) {                    \
      bf16x4 va = *(const bf16x4*)(vfr[c] + (P) * 4096 + dt * 1024);          \
      _Pragma("unroll") for (int qt = 0; qt < 2; ++qt)                        \
          Ot[dt][qt] = MFMA16K16(va, pb[qt][c], Ot[dt][qt]);                  \
    }                                                                         \
    __syncthreads();                                                          \
    kv += 64;                                                                 \
  }

  for (int it = 0; it < SS / 128; ++it) {
    ATTN_STEP(0);
    ATTN_STEP(1);
  }
#undef ATTN_STEP

  // final normalizer: every lane's Os[qt] rows all hold the full kv-sum
  float inv[2];
#pragma unroll
  for (int qt = 0; qt < 2; ++qt) inv[qt] = 1.0f / Os[qt][0];

  // write O^T: per lane q = l16 (fixed), d = dt*16 + quad*4 + r (contiguous)
#pragma unroll
  for (int qt = 0; qt < 2; ++qt) {
    int q = q0 + wave * 32 + qt * 16 + l16;
    size_t ob = ((size_t)b * SS + q) * DM + h * DH;
#pragma unroll
    for (int dt = 0; dt < 4; ++dt) {
      uintx2 o;
      o[0] = pack2bf(Ot[dt][qt][0] * inv[qt], Ot[dt][qt][1] * inv[qt]);
      o[1] = pack2bf(Ot[dt][qt][2] * inv[qt], Ot[dt][qt][3] * inv[qt]);
      *(uintx2*)(&ctx[ob + dt * 16 + quad * 4]) = o;
    }
  }
}

extern "C" void kernel_launch(void* const* d_in, const int* in_sizes, int n_in,
                              void* d_out, int out_size, void* d_ws, size_t ws_size,
                              hipStream_t stream) {
  const float* x  = (const float*)d_in[0];
  const float* Wq = (const float*)d_in[1];
  const float* bq = (const float*)d_in[2];
  const float* Wk = (const float*)d_in[3];
  const float* bk = (const float*)d_in[4];
  const float* Wv = (const float*)d_in[5];
  const float* bv = (const float*)d_in[6];
  const float* Wo = (const float*)d_in[7];
  const float* bo = (const float*)d_in[8];
  float* out = (float*)d_out;

  char* ws = (char*)d_ws;
  u16* xb = (u16*)(ws);                        // 16 MB  [8192,1024] bf16
  u16* Wt = (u16*)(ws + (16u << 20));          //  8 MB  [4096,1024] bf16
  u16* Qb = (u16*)(ws + (24u << 20));          // 16 MB  [B,H,S,Dh] (pre-scaled)
  u16* Kb = (u16*)(ws + (40u << 20));          // 16 MB  [B,H,S,Dh]
  u16* VT = (u16*)(ws + (56u << 20));          // 16 MB  [B,H,Dh,S]
  u16* Cb = (u16*)(ws + (72u << 20));          // 16 MB  [B,S,D] bf16 ctx

  k_cvt_x<<<MROWS * DM / 1024, 256, 0, stream>>>(x, xb);
  k_tw<<<dim3(32, 128), dim3(32, 32), 0, stream>>>(Wq, Wk, Wv, Wo, Wt);
  k_gemm<<<dim3(MROWS / 128, 24), 256, 0, stream>>>(
      xb, Wt, MROWS, 3 * DM, DM, bq, bk, bv, Qb, Kb, VT, nullptr, 1);
  k_attn<<<dim3(SS / 128, NH, BB), 256, 0, stream>>>(Qb, Kb, VT, Cb);
  k_gemm<<<dim3(MROWS / 128, 8), 256, 0, stream>>>(
      Cb, Wt + (size_t)3 * DM * DM, MROWS, DM, DM, bo, nullptr, nullptr,
      nullptr, nullptr, nullptr, out, 0);
}

// Round 3
// 315.431 us; speedup vs baseline: 1.0048x; 1.0048x over previous
//
#include <hip/hip_runtime.h>
#include <hip/hip_bf16.h>

#define DM 1024
#define NH 16
#define DH 64
#define BB 4
#define SS 2048
#define MROWS (BB*SS)   // 8192

typedef unsigned short u16;
typedef short bf16x8 __attribute__((ext_vector_type(8)));
typedef short bf16x4 __attribute__((ext_vector_type(4)));
typedef float f32x4 __attribute__((ext_vector_type(4)));
typedef unsigned uintx2 __attribute__((ext_vector_type(2)));

#define MFMA16(a, b, c) __builtin_amdgcn_mfma_f32_16x16x32_bf16((a), (b), (c), 0, 0, 0)
#define MFMA16K16(a, b, c) __builtin_amdgcn_mfma_f32_16x16x16bf16_1k((a), (b), (c), 0, 0, 0)

__device__ __forceinline__ u16 f2bf(float f) {
  union { float f; unsigned u; } v; v.f = f;
  unsigned u = v.u;
  return (u16)((u + 0x7fffu + ((u >> 16) & 1u)) >> 16);
}

// pack two floats -> u32 of two RNE bf16 (lo = a, hi = b)
__device__ __forceinline__ unsigned pack2bf(float a, float b) {
  __hip_bfloat162 h = __float22bfloat162_rn(make_float2(a, b));
  unsigned u;
  __builtin_memcpy(&u, &h, 4);
  return u;
}

__device__ __forceinline__ bf16x8 ld_bf8(const u16* p) {
  return *(const bf16x8*)p;
}

// ---------------- convert x (fp32 -> bf16), 4 elems/thread ----------------
__global__ __launch_bounds__(256) void k_cvt_x(const float* __restrict__ x,
                                               u16* __restrict__ xb) {
  int i = (blockIdx.x * 256 + threadIdx.x) * 4;
  float4 v = *(const float4*)(x + i);
  ushort4 o;
  o.x = f2bf(v.x); o.y = f2bf(v.y); o.z = f2bf(v.z); o.w = f2bf(v.w);
  *(ushort4*)(xb + i) = o;
}

// ------------- transpose weights W[K,N] -> Wt[N,K] bf16, 4 segments -------
__global__ __launch_bounds__(1024) void k_tw(const float* __restrict__ Wq,
                                             const float* __restrict__ Wk,
                                             const float* __restrict__ Wv,
                                             const float* __restrict__ Wo,
                                             u16* __restrict__ Wt) {
  __shared__ float t[32][33];
  int k0 = blockIdx.x * 32;
  int seg = blockIdx.y >> 5;
  int n0 = (blockIdx.y & 31) * 32;
  const float* W = seg == 0 ? Wq : seg == 1 ? Wk : seg == 2 ? Wv : Wo;
  int tx = threadIdx.x, ty = threadIdx.y;
  t[ty][tx] = W[(size_t)(k0 + ty) * DM + n0 + tx];
  __syncthreads();
  Wt[(size_t)(seg * DM + n0 + ty) * DM + k0 + tx] = f2bf(t[tx][ty]);
}

// ---------------- GEMM: C[M,N] = A[M,K] * Bt[N,K]^T + bias ----------------
// (unchanged)
__global__ __launch_bounds__(256) void k_gemm(
    const u16* __restrict__ A, const u16* __restrict__ Bt,
    int M, int N, int K,
    const float* __restrict__ b0, const float* __restrict__ b1,
    const float* __restrict__ b2,
    u16* __restrict__ oq, u16* __restrict__ ok, u16* __restrict__ ov,
    float* __restrict__ of, int mode) {
  __shared__ __align__(16) u16 As[128 * 32];
  __shared__ __align__(16) u16 Bs[128 * 32];
  int tid = threadIdx.x;
  int wave = tid >> 6, lane = tid & 63, quad = lane >> 4, l16 = lane & 15;
  int bm = blockIdx.x * 128, bn = blockIdx.y * 128;
  int wr = (wave >> 1) * 64, wc = (wave & 1) * 64;
  f32x4 acc[4][4] = {};

  const u16* ga = A + (size_t)(bm + wave * 32 + (lane >> 2)) * K + (lane & 3) * 8;
  const u16* gb = Bt + (size_t)(bn + wave * 32 + (lane >> 2)) * K + (lane & 3) * 8;
  u16* lda = &As[wave * 1024];
  u16* ldb = &Bs[wave * 1024];

  for (int k0 = 0; k0 < K; k0 += 32) {
#pragma unroll
    for (int i = 0; i < 2; ++i) {
      __builtin_amdgcn_global_load_lds(
          (const __attribute__((address_space(1))) void*)(ga + (size_t)i * 16 * K + k0),
          (__attribute__((address_space(3))) void*)(lda + i * 512), 16, 0, 0);
      __builtin_amdgcn_global_load_lds(
          (const __attribute__((address_space(1))) void*)(gb + (size_t)i * 16 * K + k0),
          (__attribute__((address_space(3))) void*)(ldb + i * 512), 16, 0, 0);
    }
    __syncthreads();
    bf16x8 af[4], bfr[4];
#pragma unroll
    for (int mi = 0; mi < 4; ++mi)
      af[mi] = *(const bf16x8*)(&As[(wr + mi * 16 + l16) * 32 + quad * 8]);
#pragma unroll
    for (int ni = 0; ni < 4; ++ni)
      bfr[ni] = *(const bf16x8*)(&Bs[(wc + ni * 16 + l16) * 32 + quad * 8]);
#pragma unroll
    for (int mi = 0; mi < 4; ++mi)
#pragma unroll
      for (int ni = 0; ni < 4; ++ni)
        acc[mi][ni] = MFMA16(af[mi], bfr[ni], acc[mi][ni]);
    __syncthreads();
  }

  if (mode == 0) {
#pragma unroll
    for (int mi = 0; mi < 4; ++mi)
#pragma unroll
      for (int ni = 0; ni < 4; ++ni)
#pragma unroll
        for (int r = 0; r < 4; ++r) {
          int row = bm + wr + mi * 16 + quad * 4 + r;
          int col = bn + wc + ni * 16 + l16;
          of[(size_t)row * N + col] = acc[mi][ni][r] + b0[col];
        }
  } else {
    int seg = bn >> 10;
    const float* bia = seg == 0 ? b0 : seg == 1 ? b1 : b2;
    int cb = bn & 1023;
    if (seg == 2) {
#pragma unroll
      for (int mi = 0; mi < 4; ++mi)
#pragma unroll
        for (int ni = 0; ni < 4; ++ni) {
          int row = bm + wr + mi * 16 + quad * 4;
          int col = cb + wc + ni * 16 + l16;
          float bv_ = bia[col];
          int bb2 = row >> 11, s = row & 2047, hh = col >> 6, dh = col & 63;
          ushort4 o4;
          o4.x = f2bf(acc[mi][ni][0] + bv_);
          o4.y = f2bf(acc[mi][ni][1] + bv_);
          o4.z = f2bf(acc[mi][ni][2] + bv_);
          o4.w = f2bf(acc[mi][ni][3] + bv_);
          *(ushort4*)(&ov[(((size_t)bb2 * NH + hh) * DH + dh) * SS + s]) = o4;
        }
    } else {
      u16* o = seg == 0 ? oq : ok;
      float sc = seg == 0 ? (0.125f * 1.44269504f) : 1.0f;
#pragma unroll
      for (int mi = 0; mi < 4; ++mi)
#pragma unroll
        for (int ni = 0; ni < 4; ++ni)
#pragma unroll
          for (int r = 0; r < 4; ++r) {
            int row = bm + wr + mi * 16 + quad * 4 + r;
            int col = cb + wc + ni * 16 + l16;
            float v = (acc[mi][ni][r] + bia[col]) * sc;
            int bb2 = row >> 11, s = row & 2047, hh = col >> 6, dh = col & 63;
            o[((((size_t)bb2 * NH + hh) * SS) + s) * DH + dh] = f2bf(v);
          }
    }
  }
}

// ---------------- flash attention (transposed-S, register P, DMA staging) --
// grid: (S/128, NH, BB), block 256 (4 waves, 32 q-rows each)
// R9 changes vs R8:
//  - REVERT normalizer to VALU lrun (R8's MFMA-of-ones added MFMA-pipe work
//    + 12 VGPR and measured +5us; lrun keeps truncated-sum semantics).
//  - KEEP XCD swizzle (FETCH 139->24.6 MB) + DMA-at-top.
//  - NEW: per-block kv-tile start rotation. MfmaUtil+VALUBusy summed to ~90%
//    with neither >46% -> barrier lockstep phase-locks all co-resident blocks
//    into {all-MFMA} / {all-exp} phases that cannot overlap. Rotating each
//    block's kv start (co-resident blocks staggered by 8 tiles) lets one
//    block's MFMA phase overlap another's exp phase. Tile order is
//    math-order only (no running max), fp reassociation ~1e-6 << 2^-9 floor.
//  - NEW: s_setprio(1) around QK and PV MFMA clusters (T5; arbitrates
//    MFMA-phase waves over exp-phase waves across desynced blocks).
__global__ __launch_bounds__(256) void k_attn(const u16* __restrict__ Q,
                                              const u16* __restrict__ Kg,
                                              const u16* __restrict__ VT,
                                              u16* __restrict__ ctx) {
  __shared__ __align__(16) u16 Ks[2][64][64];
  __shared__ __align__(16) u16 Vts[2][64][64];  // [d][kv], swizzled
  int tid = threadIdx.x;
  int wave = tid >> 6, lane = tid & 63, quad = lane >> 4, l16 = lane & 15;
  // XCD-aware remap: all 16 q-tiles of one (b,h) on one XCD (KV L2-resident).
  int g = blockIdx.x + gridDim.x * (blockIdx.y + gridDim.y * blockIdx.z);
  int xcd = g & 7, iw = g >> 3;
  int bh = xcd * 8 + (iw >> 4);  // 0..63
  int qtile = iw & 15;
  int h = bh & 15, b = bh >> 4;
  int q0 = qtile * 128;
  // kv start rotation: blocks +32 apart in iw (co-resident on a CU under RR
  // intra-XCD dispatch) get starts 8 tiles apart; consecutive iw +3 jitter.
  int st0 = (((iw >> 5) << 3) + (iw & 31) * 3) & 31;
  size_t bhoff = ((size_t)b * NH + h) * SS * DH;
  const u16* Qp = Q + bhoff + (size_t)(q0 + wave * 32) * DH;
  const u16* Kp = Kg + bhoff;
  const u16* Vp = VT + ((size_t)b * NH + h) * DH * SS;  // [Dh][S]

  // Q as B-operand fragments: B[k=d=quad*8+j][n=q=l16], 2 q-tiles
  bf16x8 qf[2][2];
#pragma unroll
  for (int qt = 0; qt < 2; ++qt) {
    qf[qt][0] = ld_bf8(Qp + (qt * 16 + l16) * DH + quad * 8);
    qf[qt][1] = ld_bf8(Qp + (qt * 16 + l16) * DH + 32 + quad * 8);
  }

  f32x4 Ot[4][2] = {};           // [d-tile][q-tile], O^T C-layout
  float lrun[2] = {0.0f, 0.0f};  // per-lane partial sums (q = l16)
  const f32x4 fz = {0.0f, 0.0f, 0.0f, 0.0f};

  // ---- staging constants (global side carries the swizzle) ----
  int lrow = lane >> 3;            // 0..7 (row within 8-row DMA chunk)
  int lcb = (lane & 7) ^ lrow;     // swizzled global col-block
  const u16* kdma[2];
  const u16* vdma[2];
  u16* kl[2];
  u16* vl[2];
#pragma unroll
  for (int i = 0; i < 2; ++i) {
    int chunk = wave * 2 + i;      // 0..7, 8 rows each
    kdma[i] = Kp + (size_t)(chunk * 8 + lrow) * DH + lcb * 8;
    vdma[i] = Vp + (size_t)(chunk * 8 + lrow) * SS + lcb * 8;
    kl[i] = &Ks[0][chunk * 8][0];
    vl[i] = &Vts[0][chunk * 8][0];
  }

  // ---- hoisted frag pointers (loop addressing = base + literal) ----
  int e7 = l16 & 7, qh = quad >> 1, qp = quad & 1;
  const u16* kfr0 = &Ks[0][l16][(quad ^ e7) * 8];        // d-blocks 0..3
  const u16* kfr1 = &Ks[0][l16][((quad + 4) ^ e7) * 8];  // d-blocks 4..7
  const u16* vfr[4];
#pragma unroll
  for (int c = 0; c < 4; ++c)
    vfr[c] = &Vts[0][l16][((2 * c + qh) ^ e7) * 8 + qp * 4];

  // ---- prestage tile st0 into buffer 0 ----
  {
    size_t ko0 = (size_t)st0 * (64 * DH);
    size_t vo0 = (size_t)st0 * 64;
#pragma unroll
    for (int i = 0; i < 2; ++i) {
      __builtin_amdgcn_global_load_lds(
          (const __attribute__((address_space(1))) void*)(kdma[i] + ko0),
          (__attribute__((address_space(3))) void*)kl[i], 16, 0, 0);
      __builtin_amdgcn_global_load_lds(
          (const __attribute__((address_space(1))) void*)(vdma[i] + vo0),
          (__attribute__((address_space(3))) void*)vl[i], 16, 0, 0);
    }
  }
  __syncthreads();

#define ATTN_STEP(P, I)                                                       \
  {                                                                           \
    if ((I) < 31) {                                                           \
      int nxt = (st0 + (I) + 1) & 31;                                         \
      size_t ko = (size_t)nxt * (64 * DH);                                    \
      size_t vo = (size_t)nxt * 64;                                           \
      _Pragma("unroll") for (int i = 0; i < 2; ++i) {                         \
        __builtin_amdgcn_global_load_lds(                                     \
            (const __attribute__((address_space(1))) void*)(kdma[i] + ko),    \
            (__attribute__((address_space(3))) void*)(kl[i] +                 \
                                                      (1 - (P)) * 4096),      \
            16, 0, 0);                                                        \
        __builtin_amdgcn_global_load_lds(                                     \
            (const __attribute__((address_space(1))) void*)(vdma[i] + vo),    \
            (__attribute__((address_space(3))) void*)(vl[i] +                 \
                                                      (1 - (P)) * 4096),      \
            16, 0, 0);                                                        \
      }                                                                       \
    }                                                                         \
    f32x4 s[2][4];                                                            \
    __builtin_amdgcn_s_setprio(1);                                            \
    _Pragma("unroll") for (int t = 0; t < 4; ++t) {                           \
      bf16x8 kb0 = *(const bf16x8*)(kfr0 + (P) * 4096 + t * 1024);            \
      bf16x8 kb1 = *(const bf16x8*)(kfr1 + (P) * 4096 + t * 1024);            \
      _Pragma("unroll") for (int qt = 0; qt < 2; ++qt) {                      \
        f32x4 z = MFMA16(kb0, qf[qt][0], fz);                                 \
        z = MFMA16(kb1, qf[qt][1], z);                                        \
        s[qt][t] = z;                                                         \
      }                                                                       \
    }                                                                         \
    __builtin_amdgcn_s_setprio(0);                                            \
    bf16x4 pb[2][4];                                                          \
    _Pragma("unroll") for (int qt = 0; qt < 2; ++qt)                          \
        _Pragma("unroll") for (int t = 0; t < 4; ++t) {                       \
      unsigned u0 = __builtin_bit_cast(                                       \
          unsigned, __builtin_amdgcn_exp2f(s[qt][t][0]));                     \
      unsigned u1 = __builtin_bit_cast(                                       \
          unsigned, __builtin_amdgcn_exp2f(s[qt][t][1]));                     \
      unsigned u2 = __builtin_bit_cast(                                       \
          unsigned, __builtin_amdgcn_exp2f(s[qt][t][2]));                     \
      unsigned u3 = __builtin_bit_cast(                                       \
          unsigned, __builtin_amdgcn_exp2f(s[qt][t][3]));                     \
      unsigned w0 = __builtin_amdgcn_perm(u1, u0, 0x07060302u);               \
      unsigned w1 = __builtin_amdgcn_perm(u3, u2, 0x07060302u);               \
      lrun[qt] += __builtin_bit_cast(float, w0 << 16) +                       \
                  __builtin_bit_cast(float, w0 & 0xffff0000u) +               \
                  __builtin_bit_cast(float, w1 << 16) +                       \
                  __builtin_bit_cast(float, w1 & 0xffff0000u);                \
      uintx2 w;                                                               \
      w[0] = w0;                                                              \
      w[1] = w1;                                                              \
      pb[qt][t] = __builtin_bit_cast(bf16x4, w);                              \
    }                                                                         \
    __builtin_amdgcn_s_setprio(1);                                            \
    _Pragma("unroll") for (int c = 0; c < 4; ++c)                             \
        _Pragma("unroll") for (int dt = 0; dt < 4; ++dt) {                    \
      bf16x4 va = *(const bf16x4*)(vfr[c] + (P) * 4096 + dt * 1024);          \
      _Pragma("unroll") for (int qt = 0; qt < 2; ++qt)                        \
          Ot[dt][qt] = MFMA16K16(va, pb[qt][c], Ot[dt][qt]);                  \
    }                                                                         \
    __builtin_amdgcn_s_setprio(0);                                            \
    __syncthreads();                                                          \
  }

  for (int it = 0; it < 32; it += 2) {
    ATTN_STEP(0, it);
    ATTN_STEP(1, it + 1);
  }
#undef ATTN_STEP

  // final normalizer: lanes {l16, +16, +32, +48} hold q=l16 partials
  float inv[2];
#pragma unroll
  for (int qt = 0; qt < 2; ++qt) {
    float l = lrun[qt];
    l += __shfl_xor(l, 16);
    l += __shfl_xor(l, 32);
    inv[qt] = 1.0f / l;
  }

  // write O^T: per lane q = l16 (fixed), d = dt*16 + quad*4 + r (contiguous)
#pragma unroll
  for (int qt = 0; qt < 2; ++qt) {
    int q = q0 + wave * 32 + qt * 16 + l16;
    size_t ob = ((size_t)b * SS + q) * DM + h * DH;
#pragma unroll
    for (int dt = 0; dt < 4; ++dt) {
      uintx2 o;
      o[0] = pack2bf(Ot[dt][qt][0] * inv[qt], Ot[dt][qt][1] * inv[qt]);
      o[1] = pack2bf(Ot[dt][qt][2] * inv[qt], Ot[dt][qt][3] * inv[qt]);
      *(uintx2*)(&ctx[ob + dt * 16 + quad * 4]) = o;
    }
  }
}

extern "C" void kernel_launch(void* const* d_in, const int* in_sizes, int n_in,
                              void* d_out, int out_size, void* d_ws, size_t ws_size,
                              hipStream_t stream) {
  const float* x  = (const float*)d_in[0];
  const float* Wq = (const float*)d_in[1];
  const float* bq = (const float*)d_in[2];
  const float* Wk = (const float*)d_in[3];
  const float* bk = (const float*)d_in[4];
  const float* Wv = (const float*)d_in[5];
  const float* bv = (const float*)d_in[6];
  const float* Wo = (const float*)d_in[7];
  const float* bo = (const float*)d_in[8];
  float* out = (float*)d_out;

  char* ws = (char*)d_ws;
  u16* xb = (u16*)(ws);                        // 16 MB  [8192,1024] bf16
  u16* Wt = (u16*)(ws + (16u << 20));          //  8 MB  [4096,1024] bf16
  u16* Qb = (u16*)(ws + (24u << 20));          // 16 MB  [B,H,S,Dh] (pre-scaled)
  u16* Kb = (u16*)(ws + (40u << 20));          // 16 MB  [B,H,S,Dh]
  u16* VT = (u16*)(ws + (56u << 20));          // 16 MB  [B,H,Dh,S]
  u16* Cb = (u16*)(ws + (72u << 20));          // 16 MB  [B,S,D] bf16 ctx

  k_cvt_x<<<MROWS * DM / 1024, 256, 0, stream>>>(x, xb);
  k_tw<<<dim3(32, 128), dim3(32, 32), 0, stream>>>(Wq, Wk, Wv, Wo, Wt);
  k_gemm<<<dim3(MROWS / 128, 24), 256, 0, stream>>>(
      xb, Wt, MROWS, 3 * DM, DM, bq, bk, bv, Qb, Kb, VT, nullptr, 1);
  k_attn<<<dim3(SS / 128, NH, BB), 256, 0, stream>>>(Qb, Kb, VT, Cb);
  k_gemm<<<dim3(MROWS / 128, 8), 256, 0, stream>>>(
      Cb, Wt + (size_t)3 * DM * DM, MROWS, DM, DM, bo, nullptr, nullptr,
      nullptr, nullptr, nullptr, out, 0);
}

// Round 4
// 310.114 us; speedup vs baseline: 1.0221x; 1.0171x over previous
//
#include <hip/hip_runtime.h>
#include <hip/hip_bf16.h>

#define DM 1024
#define NH 16
#define DH 64
#define BB 4
#define SS 2048
#define MROWS (BB*SS)   // 8192

typedef unsigned short u16;
typedef short bf16x8 __attribute__((ext_vector_type(8)));
typedef short bf16x4 __attribute__((ext_vector_type(4)));
typedef float f32x4 __attribute__((ext_vector_type(4)));
typedef unsigned uintx2 __attribute__((ext_vector_type(2)));

#define MFMA16(a, b, c) __builtin_amdgcn_mfma_f32_16x16x32_bf16((a), (b), (c), 0, 0, 0)
#define MFMA16K16(a, b, c) __builtin_amdgcn_mfma_f32_16x16x16bf16_1k((a), (b), (c), 0, 0, 0)

__device__ __forceinline__ u16 f2bf(float f) {
  union { float f; unsigned u; } v; v.f = f;
  unsigned u = v.u;
  return (u16)((u + 0x7fffu + ((u >> 16) & 1u)) >> 16);
}

// pack two floats -> u32 of two RNE bf16 (lo = a, hi = b)
__device__ __forceinline__ unsigned pack2bf(float a, float b) {
  __hip_bfloat162 h = __float22bfloat162_rn(make_float2(a, b));
  unsigned u;
  __builtin_memcpy(&u, &h, 4);
  return u;
}

__device__ __forceinline__ bf16x8 ld_bf8(const u16* p) {
  return *(const bf16x8*)p;
}

// ---------------- convert x (fp32 -> bf16), 4 elems/thread ----------------
__global__ __launch_bounds__(256) void k_cvt_x(const float* __restrict__ x,
                                               u16* __restrict__ xb) {
  int i = (blockIdx.x * 256 + threadIdx.x) * 4;
  float4 v = *(const float4*)(x + i);
  ushort4 o;
  o.x = f2bf(v.x); o.y = f2bf(v.y); o.z = f2bf(v.z); o.w = f2bf(v.w);
  *(ushort4*)(xb + i) = o;
}

// ------------- transpose weights W[K,N] -> Wt[N,K] bf16, 4 segments -------
__global__ __launch_bounds__(1024) void k_tw(const float* __restrict__ Wq,
                                             const float* __restrict__ Wk,
                                             const float* __restrict__ Wv,
                                             const float* __restrict__ Wo,
                                             u16* __restrict__ Wt) {
  __shared__ float t[32][33];
  int k0 = blockIdx.x * 32;
  int seg = blockIdx.y >> 5;
  int n0 = (blockIdx.y & 31) * 32;
  const float* W = seg == 0 ? Wq : seg == 1 ? Wk : seg == 2 ? Wv : Wo;
  int tx = threadIdx.x, ty = threadIdx.y;
  t[ty][tx] = W[(size_t)(k0 + ty) * DM + n0 + tx];
  __syncthreads();
  Wt[(size_t)(seg * DM + n0 + ty) * DM + k0 + tx] = f2bf(t[tx][ty]);
}

// ---------------- GEMM: C[M,N] = A[M,K] * Bt[N,K]^T + bias ----------------
// (unchanged)
__global__ __launch_bounds__(256) void k_gemm(
    const u16* __restrict__ A, const u16* __restrict__ Bt,
    int M, int N, int K,
    const float* __restrict__ b0, const float* __restrict__ b1,
    const float* __restrict__ b2,
    u16* __restrict__ oq, u16* __restrict__ ok, u16* __restrict__ ov,
    float* __restrict__ of, int mode) {
  __shared__ __align__(16) u16 As[128 * 32];
  __shared__ __align__(16) u16 Bs[128 * 32];
  int tid = threadIdx.x;
  int wave = tid >> 6, lane = tid & 63, quad = lane >> 4, l16 = lane & 15;
  int bm = blockIdx.x * 128, bn = blockIdx.y * 128;
  int wr = (wave >> 1) * 64, wc = (wave & 1) * 64;
  f32x4 acc[4][4] = {};

  const u16* ga = A + (size_t)(bm + wave * 32 + (lane >> 2)) * K + (lane & 3) * 8;
  const u16* gb = Bt + (size_t)(bn + wave * 32 + (lane >> 2)) * K + (lane & 3) * 8;
  u16* lda = &As[wave * 1024];
  u16* ldb = &Bs[wave * 1024];

  for (int k0 = 0; k0 < K; k0 += 32) {
#pragma unroll
    for (int i = 0; i < 2; ++i) {
      __builtin_amdgcn_global_load_lds(
          (const __attribute__((address_space(1))) void*)(ga + (size_t)i * 16 * K + k0),
          (__attribute__((address_space(3))) void*)(lda + i * 512), 16, 0, 0);
      __builtin_amdgcn_global_load_lds(
          (const __attribute__((address_space(1))) void*)(gb + (size_t)i * 16 * K + k0),
          (__attribute__((address_space(3))) void*)(ldb + i * 512), 16, 0, 0);
    }
    __syncthreads();
    bf16x8 af[4], bfr[4];
#pragma unroll
    for (int mi = 0; mi < 4; ++mi)
      af[mi] = *(const bf16x8*)(&As[(wr + mi * 16 + l16) * 32 + quad * 8]);
#pragma unroll
    for (int ni = 0; ni < 4; ++ni)
      bfr[ni] = *(const bf16x8*)(&Bs[(wc + ni * 16 + l16) * 32 + quad * 8]);
#pragma unroll
    for (int mi = 0; mi < 4; ++mi)
#pragma unroll
      for (int ni = 0; ni < 4; ++ni)
        acc[mi][ni] = MFMA16(af[mi], bfr[ni], acc[mi][ni]);
    __syncthreads();
  }

  if (mode == 0) {
#pragma unroll
    for (int mi = 0; mi < 4; ++mi)
#pragma unroll
      for (int ni = 0; ni < 4; ++ni)
#pragma unroll
        for (int r = 0; r < 4; ++r) {
          int row = bm + wr + mi * 16 + quad * 4 + r;
          int col = bn + wc + ni * 16 + l16;
          of[(size_t)row * N + col] = acc[mi][ni][r] + b0[col];
        }
  } else {
    int seg = bn >> 10;
    const float* bia = seg == 0 ? b0 : seg == 1 ? b1 : b2;
    int cb = bn & 1023;
    if (seg == 2) {
#pragma unroll
      for (int mi = 0; mi < 4; ++mi)
#pragma unroll
        for (int ni = 0; ni < 4; ++ni) {
          int row = bm + wr + mi * 16 + quad * 4;
          int col = cb + wc + ni * 16 + l16;
          float bv_ = bia[col];
          int bb2 = row >> 11, s = row & 2047, hh = col >> 6, dh = col & 63;
          ushort4 o4;
          o4.x = f2bf(acc[mi][ni][0] + bv_);
          o4.y = f2bf(acc[mi][ni][1] + bv_);
          o4.z = f2bf(acc[mi][ni][2] + bv_);
          o4.w = f2bf(acc[mi][ni][3] + bv_);
          *(ushort4*)(&ov[(((size_t)bb2 * NH + hh) * DH + dh) * SS + s]) = o4;
        }
    } else {
      u16* o = seg == 0 ? oq : ok;
      float sc = seg == 0 ? (0.125f * 1.44269504f) : 1.0f;
#pragma unroll
      for (int mi = 0; mi < 4; ++mi)
#pragma unroll
        for (int ni = 0; ni < 4; ++ni)
#pragma unroll
          for (int r = 0; r < 4; ++r) {
            int row = bm + wr + mi * 16 + quad * 4 + r;
            int col = cb + wc + ni * 16 + l16;
            float v = (acc[mi][ni][r] + bia[col]) * sc;
            int bb2 = row >> 11, s = row & 2047, hh = col >> 6, dh = col & 63;
            o[((((size_t)bb2 * NH + hh) * SS) + s) * DH + dh] = f2bf(v);
          }
    }
  }
}

// ---------------- flash attention (transposed-S, register P, DMA staging) --
// grid: (S/128, NH, BB), block 256 (4 waves, 32 q-rows each)
// R10 changes vs R0 (the 105us best; R8/R9 experiments reverted):
//  - ONE variable: 4 LDS tile-slots (64 KB), barrier every 2 kv-tiles
//    instead of every tile (16 barriers vs 32). MfmaUtil 41 + VALUBusy 51
//    ~= 92 with neither pipe saturated -> pipes are additive, not
//    overlapped: the per-tile __syncthreads re-lockstops the 4 waves every
//    ~800 cyc, erasing the drift that would let one wave's exp phase run
//    under another's MFMA phase. Doubling the barrier window doubles the
//    drift budget.
//  Hazard audit: slot s staged in a step is consumed only after an
//  intervening barrier (which also drains vmcnt); slot readers always
//  finish before the barrier that precedes the slot's re-stage:
//    iter: STEP(s0,d2) STEP(s1,d3) BAR STEP(s2,d0) STEP(s3,d1) BAR
//  - slot0 read in STEP0; re-staged in STEP2 (after BAR) ok
//  - slot2 staged in STEP0; read in STEP2 (after BAR, vmcnt drained) ok
__global__ __launch_bounds__(256) void k_attn(const u16* __restrict__ Q,
                                              const u16* __restrict__ Kg,
                                              const u16* __restrict__ VT,
                                              u16* __restrict__ ctx) {
  __shared__ __align__(16) u16 Ks[4][64][64];   // 32 KB, 4 kv-tile slots
  __shared__ __align__(16) u16 Vts[4][64][64];  // 32 KB, [d][kv], swizzled
  int tid = threadIdx.x;
  int wave = tid >> 6, lane = tid & 63, quad = lane >> 4, l16 = lane & 15;
  int q0 = blockIdx.x * 128;
  int h = blockIdx.y, b = blockIdx.z;
  size_t bh = ((size_t)b * NH + h) * SS * DH;
  const u16* Qp = Q + bh + (size_t)(q0 + wave * 32) * DH;
  const u16* Kp = Kg + bh;
  const u16* Vp = VT + ((size_t)b * NH + h) * DH * SS;  // [Dh][S]

  // Q as B-operand fragments: B[k=d=quad*8+j][n=q=l16], 2 q-tiles
  bf16x8 qf[2][2];
#pragma unroll
  for (int qt = 0; qt < 2; ++qt) {
    qf[qt][0] = ld_bf8(Qp + (qt * 16 + l16) * DH + quad * 8);
    qf[qt][1] = ld_bf8(Qp + (qt * 16 + l16) * DH + 32 + quad * 8);
  }

  f32x4 Ot[4][2] = {};           // [d-tile][q-tile], O^T C-layout
  float lrun[2] = {0.0f, 0.0f};  // per-lane partial sums (q = l16)

  // ---- staging constants (global side carries the swizzle) ----
  int lrow = lane >> 3;            // 0..7 (row within 8-row DMA chunk)
  int lcb = (lane & 7) ^ lrow;     // swizzled global col-block
  const u16* kdma[2];
  const u16* vdma[2];
  u16* kl[2];
  u16* vl[2];
#pragma unroll
  for (int i = 0; i < 2; ++i) {
    int chunk = wave * 2 + i;      // 0..7, 8 rows each
    kdma[i] = Kp + (size_t)(chunk * 8 + lrow) * DH + lcb * 8;
    vdma[i] = Vp + (size_t)(chunk * 8 + lrow) * SS + lcb * 8;
    kl[i] = &Ks[0][chunk * 8][0];
    vl[i] = &Vts[0][chunk * 8][0];
  }

  // ---- hoisted frag pointers (loop addressing = base + literal) ----
  int e7 = l16 & 7, qh = quad >> 1, qp = quad & 1;
  const u16* kfr0 = &Ks[0][l16][(quad ^ e7) * 8];        // d-blocks 0..3
  const u16* kfr1 = &Ks[0][l16][((quad + 4) ^ e7) * 8];  // d-blocks 4..7
  const u16* vfr[4];
#pragma unroll
  for (int c = 0; c < 4; ++c)
    vfr[c] = &Vts[0][l16][((2 * c + qh) ^ e7) * 8 + qp * 4];

  // ---- prestage tiles 0,1 into slots 0,1 ----
#pragma unroll
  for (int i = 0; i < 2; ++i) {
    __builtin_amdgcn_global_load_lds(
        (const __attribute__((address_space(1))) void*)kdma[i],
        (__attribute__((address_space(3))) void*)kl[i], 16, 0, 0);
    __builtin_amdgcn_global_load_lds(
        (const __attribute__((address_space(1))) void*)vdma[i],
        (__attribute__((address_space(3))) void*)vl[i], 16, 0, 0);
    __builtin_amdgcn_global_load_lds(
        (const __attribute__((address_space(1))) void*)(kdma[i] + 64 * DH),
        (__attribute__((address_space(3))) void*)(kl[i] + 4096), 16, 0, 0);
    __builtin_amdgcn_global_load_lds(
        (const __attribute__((address_space(1))) void*)(vdma[i] + 64),
        (__attribute__((address_space(3))) void*)(vl[i] + 4096), 16, 0, 0);
  }
  __syncthreads();

  int kv = 128;  // next tile (by kv offset) to stage

#define ATTN_STEP(SLOT, DST, BAR)                                             \
  {                                                                           \
    f32x4 s[2][4];                                                            \
    _Pragma("unroll") for (int t = 0; t < 4; ++t) {                           \
      bf16x8 kb0 = *(const bf16x8*)(kfr0 + (SLOT) * 4096 + t * 1024);         \
      bf16x8 kb1 = *(const bf16x8*)(kfr1 + (SLOT) * 4096 + t * 1024);         \
      _Pragma("unroll") for (int qt = 0; qt < 2; ++qt) {                      \
        f32x4 z = {};                                                         \
        z = MFMA16(kb0, qf[qt][0], z);                                        \
        z = MFMA16(kb1, qf[qt][1], z);                                        \
        s[qt][t] = z;                                                         \
      }                                                                       \
    }                                                                         \
    if (kv < SS) {                                                            \
      _Pragma("unroll") for (int i = 0; i < 2; ++i) {                         \
        __builtin_amdgcn_global_load_lds(                                     \
            (const __attribute__((address_space(1))) void*)(kdma[i] +         \
                                                            (size_t)kv * DH), \
            (__attribute__((address_space(3))) void*)(kl[i] +                 \
                                                      (DST) * 4096),          \
            16, 0, 0);                                                        \
        __builtin_amdgcn_global_load_lds(                                     \
            (const __attribute__((address_space(1))) void*)(vdma[i] + kv),    \
            (__attribute__((address_space(3))) void*)(vl[i] +                 \
                                                      (DST) * 4096),          \
            16, 0, 0);                                                        \
      }                                                                       \
    }                                                                         \
    bf16x4 pb[2][4];                                                          \
    _Pragma("unroll") for (int qt = 0; qt < 2; ++qt)                          \
        _Pragma("unroll") for (int t = 0; t < 4; ++t) {                       \
      unsigned u0 = __builtin_bit_cast(                                       \
          unsigned, __builtin_amdgcn_exp2f(s[qt][t][0]));                     \
      unsigned u1 = __builtin_bit_cast(                                       \
          unsigned, __builtin_amdgcn_exp2f(s[qt][t][1]));                     \
      unsigned u2 = __builtin_bit_cast(                                       \
          unsigned, __builtin_amdgcn_exp2f(s[qt][t][2]));                     \
      unsigned u3 = __builtin_bit_cast(                                       \
          unsigned, __builtin_amdgcn_exp2f(s[qt][t][3]));                     \
      unsigned w0 = __builtin_amdgcn_perm(u1, u0, 0x07060302u);               \
      unsigned w1 = __builtin_amdgcn_perm(u3, u2, 0x07060302u);               \
      lrun[qt] += __builtin_bit_cast(float, w0 << 16) +                       \
                  __builtin_bit_cast(float, w0 & 0xffff0000u) +               \
                  __builtin_bit_cast(float, w1 << 16) +                       \
                  __builtin_bit_cast(float, w1 & 0xffff0000u);                \
      uintx2 w;                                                               \
      w[0] = w0;                                                              \
      w[1] = w1;                                                              \
      pb[qt][t] = __builtin_bit_cast(bf16x4, w);                              \
    }                                                                         \
    _Pragma("unroll") for (int c = 0; c < 4; ++c)                             \
        _Pragma("unroll") for (int dt = 0; dt < 4; ++dt) {                    \
      bf16x4 va = *(const bf16x4*)(vfr[c] + (SLOT) * 4096 + dt * 1024);       \
      _Pragma("unroll") for (int qt = 0; qt < 2; ++qt)                        \
          Ot[dt][qt] = MFMA16K16(va, pb[qt][c], Ot[dt][qt]);                  \
    }                                                                         \
    if (BAR) __syncthreads();                                                 \
    kv += 64;                                                                 \
  }

  for (int it = 0; it < 8; ++it) {
    ATTN_STEP(0, 2, 0);
    ATTN_STEP(1, 3, 1);
    ATTN_STEP(2, 0, 0);
    ATTN_STEP(3, 1, 1);
  }
#undef ATTN_STEP

  // final normalizer: lanes {l16, +16, +32, +48} hold q=l16 partials
  float inv[2];
#pragma unroll
  for (int qt = 0; qt < 2; ++qt) {
    float l = lrun[qt];
    l += __shfl_xor(l, 16);
    l += __shfl_xor(l, 32);
    inv[qt] = 1.0f / l;
  }

  // write O^T: per lane q = l16 (fixed), d = dt*16 + quad*4 + r (contiguous)
#pragma unroll
  for (int qt = 0; qt < 2; ++qt) {
    int q = q0 + wave * 32 + qt * 16 + l16;
    size_t ob = ((size_t)b * SS + q) * DM + h * DH;
#pragma unroll
    for (int dt = 0; dt < 4; ++dt) {
      uintx2 o;
      o[0] = pack2bf(Ot[dt][qt][0] * inv[qt], Ot[dt][qt][1] * inv[qt]);
      o[1] = pack2bf(Ot[dt][qt][2] * inv[qt], Ot[dt][qt][3] * inv[qt]);
      *(uintx2*)(&ctx[ob + dt * 16 + quad * 4]) = o;
    }
  }
}

extern "C" void kernel_launch(void* const* d_in, const int* in_sizes, int n_in,
                              void* d_out, int out_size, void* d_ws, size_t ws_size,
                              hipStream_t stream) {
  const float* x  = (const float*)d_in[0];
  const float* Wq = (const float*)d_in[1];
  const float* bq = (const float*)d_in[2];
  const float* Wk = (const float*)d_in[3];
  const float* bk = (const float*)d_in[4];
  const float* Wv = (const float*)d_in[5];
  const float* bv = (const float*)d_in[6];
  const float* Wo = (const float*)d_in[7];
  const float* bo = (const float*)d_in[8];
  float* out = (float*)d_out;

  char* ws = (char*)d_ws;
  u16* xb = (u16*)(ws);                        // 16 MB  [8192,1024] bf16
  u16* Wt = (u16*)(ws + (16u << 20));          //  8 MB  [4096,1024] bf16
  u16* Qb = (u16*)(ws + (24u << 20));          // 16 MB  [B,H,S,Dh] (pre-scaled)
  u16* Kb = (u16*)(ws + (40u << 20));          // 16 MB  [B,H,S,Dh]
  u16* VT = (u16*)(ws + (56u << 20));          // 16 MB  [B,H,Dh,S]
  u16* Cb = (u16*)(ws + (72u << 20));          // 16 MB  [B,S,D] bf16 ctx

  k_cvt_x<<<MROWS * DM / 1024, 256, 0, stream>>>(x, xb);
  k_tw<<<dim3(32, 128), dim3(32, 32), 0, stream>>>(Wq, Wk, Wv, Wo, Wt);
  k_gemm<<<dim3(MROWS / 128, 24), 256, 0, stream>>>(
      xb, Wt, MROWS, 3 * DM, DM, bq, bk, bv, Qb, Kb, VT, nullptr, 1);
  k_attn<<<dim3(SS / 128, NH, BB), 256, 0, stream>>>(Qb, Kb, VT, Cb);
  k_gemm<<<dim3(MROWS / 128, 8), 256, 0, stream>>>(
      Cb, Wt + (size_t)3 * DM * DM, MROWS, DM, DM, bo, nullptr, nullptr,
      nullptr, nullptr, nullptr, out, 0);
}